// Round 6
// baseline (261.552 us; speedup 1.0000x reference)
//
#include <hip/hip_runtime.h>

// Deformable depthwise 3x3 conv, B=8 C=256 H=W=96, fp32.
// Ladder: R5 166us -> R9 152us (channel-interleaved float4 gather,
//   conflicts 3.17e7 -> 1.46e7) -> R10 131us (T14 issue-early/write-late,
//   CAP=20). R6/R8 lessons: min-waves bounds / asm pipelines spill cw[9][4]
//   to HBM scratch -> plain __syncthreads + unbounded allocator only.
// R10 post-mortem: LDS pipe ~75us of 131us wall (124k base + 57k conflict
//   cy per CU); VALU 27%; HBM 20%. Biggest reducible item: conflict cycles.
// Conflict model: stride 96 f4 -> quad = xc%8 (96==0 mod 8, row drops out).
//   Offsets iid N(0,1) => adjacent lanes often duplicate xc; same xc +
//   different yc = distinct address in SAME quad = serialization. Row can
//   never rescue a collision.
// R11: pad LDS row stride to 97 float4s -> quad = (row+xc)%8 (97==1 mod 8):
//   xc-duplicates with different yc spread to different quads; baseline
//   balance preserved (consecutive xc still cycles all 8 quads). Staging
//   needs no div: chunk i of tid is row r+4i, col wcol. One-variable
//   experiment, attribution via SQ_LDS_BANK_CONFLICT (predict -> ~0.8e7).
// Tripwires: WRITE_SIZE == 73728 KB exactly; structure/barriers unchanged.

constexpr int B_ = 8, C_ = 256, H_ = 96, W_ = 96;
constexpr int HW_ = H_ * W_;
constexpr int TH = 4;              // pixel rows per block
constexpr int NT = TH * W_;        // 384 threads = 6 waves
constexpr int CSPLIT = 8;
constexpr int CPB = C_ / CSPLIT;   // 32 channels per block
constexpr int G4 = CPB / 4;        // 8 groups of 4 interleaved channels
constexpr int CAP = 20;            // window rows (typ ~14 used)
constexpr int LSTR4 = 97;          // padded row stride in float4s (97%8==1)
constexpr int NPOS = CAP * LSTR4;  // 1940 float4s = 31040 B
constexpr int NL = CAP / TH;       // 5 staging chunks per thread max

__global__ __launch_bounds__(NT) void deform_dw_conv(
    const float* __restrict__ x, const float* __restrict__ off,
    const float* __restrict__ wgt, const float* __restrict__ bias,
    float* __restrict__ out)
{
    __shared__ float4 lx4[NPOS];   // [row*97+col] = 4 channels at (row,col)
    __shared__ int s_rmin, s_rmax;

    const int tid  = threadIdx.x;
    const int r    = tid / W_;
    const int wcol = tid - r * W_;
    const int h    = blockIdx.x * TH + r;
    const int b    = blockIdx.y;
    const int c0   = blockIdx.z * CPB;

    if (tid == 0) { s_rmin = H_; s_rmax = -1; }
    __syncthreads();

    const float* offp = off + (size_t)b * 18 * HW_ + (size_t)h * W_ + wcol;

    // Per-(pixel,tap): 4 weights pre-permuted onto loaded positions
    // [0]=(yc,xc) [1]=(yc,xc+1) [2]=(yc+1,xc) [3]=(yc+1,xc+1); validity
    // folded into weights so invalid corners multiply by 0.
    float cw[9][4];
    int lofs[9];                     // yc*? + xc; padded after rmin shift
    int yy[9], xx[9];
    int myrmin = H_, myrmax = -1;

#pragma unroll
    for (int kk = 0; kk < 9; ++kk) {
        const int i = kk / 3, j = kk % 3;
        const float py = (float)(h - 1 + i) + offp[(2 * kk) * HW_];
        const float px = (float)(wcol - 1 + j) + offp[(2 * kk + 1) * HW_];
        const float fy = floorf(py), fx = floorf(px);
        const float wy = py - fy, wx = px - fx;
        const int y0 = (int)fy, x0 = (int)fx;
        const bool vy0 = (unsigned)y0 < (unsigned)H_;
        const bool vy1 = (unsigned)(y0 + 1) < (unsigned)H_;
        const bool vx0 = (unsigned)x0 < (unsigned)W_;
        const bool vx1 = (unsigned)(x0 + 1) < (unsigned)W_;
        const float w00 = (vy0 && vx0) ? (1.f - wy) * (1.f - wx) : 0.f;
        const float w01 = (vy0 && vx1) ? (1.f - wy) * wx : 0.f;
        const float w10 = (vy1 && vx0) ? wy * (1.f - wx) : 0.f;
        const float w11 = (vy1 && vx1) ? wy * wx : 0.f;
        const int yc = min(max(y0, 0), H_ - 2);
        const int xc = min(max(x0, 0), W_ - 2);
        const bool rs = (y0 == yc);
        const bool cs = (x0 == xc);
        cw[kk][0] = rs ? (cs ? w00 : w01) : (cs ? w10 : w11);
        cw[kk][1] = rs ? (cs ? w01 : w00) : (cs ? w11 : w10);
        cw[kk][2] = rs ? (cs ? w10 : w11) : (cs ? w00 : w01);
        cw[kk][3] = rs ? (cs ? w11 : w10) : (cs ? w01 : w00);
        yy[kk] = yc; xx[kk] = xc;
        myrmin = min(myrmin, yc);
        myrmax = max(myrmax, yc);
    }
    atomicMin(&s_rmin, myrmin);
    atomicMax(&s_rmax, myrmax);
    __syncthreads();
    const int rmin  = s_rmin;
    const int nrows = s_rmax + 2 - rmin;   // rows [rmin, rmax+1]
    const int pix   = h * W_ + wcol;

    if (nrows > CAP) {
        // Cold correctness path (extreme-sigma block event): direct global
        // gather; clamped coords always in-bounds, zero weights neutralize
        // invalid corners. Block-uniform branch; no barriers after this.
        const float* xp = x + (size_t)(b * C_ + c0) * HW_;
        float* op = out + (size_t)(b * C_ + c0) * HW_ + pix;
        for (int cc = 0; cc < CPB; ++cc) {
            float acc = 0.f;
#pragma unroll
            for (int kk = 0; kk < 9; ++kk) {
                const float* q = xp + yy[kk] * W_ + xx[kk];
                float s = cw[kk][0] * q[0];
                s = fmaf(cw[kk][1], q[1], s);
                s = fmaf(cw[kk][2], q[W_], s);
                s = fmaf(cw[kk][3], q[W_ + 1], s);
                acc = fmaf(wgt[(c0 + cc) * 9 + kk], s, acc);
            }
            *op = acc + bias[c0 + cc];
            xp += HW_; op += HW_;
        }
        return;
    }

    // Padded LDS offsets: row stride 97 float4s.
#pragma unroll
    for (int kk = 0; kk < 9; ++kk)
        lofs[kk] = (yy[kk] - rmin) * LSTR4 + xx[kk];

    const float* xbase = x + (size_t)(b * C_ + c0) * HW_ + rmin * W_;
    float* outb = out + (size_t)(b * C_ + c0) * HW_ + pix;

    // Transposed reg-staging: chunk i of thread tid covers (row r+4i,
    // col wcol) -- dense in global, padded (stride 97) in LDS, no division.
    float4 pf[NL];
    auto issue = [&](int g) {
        const float* p0 = xbase + (size_t)(4 * g) * HW_;
        const float* p1 = p0 + HW_;
        const float* p2 = p1 + HW_;
        const float* p3 = p2 + HW_;
#pragma unroll
        for (int i = 0; i < NL; ++i) {
            if (r + 4 * i < nrows) {
                const int p = (r + 4 * i) * W_ + wcol;
                pf[i].x = p0[p]; pf[i].y = p1[p];
                pf[i].z = p2[p]; pf[i].w = p3[p];
            }
        }
    };
    auto commit = [&]() {
#pragma unroll
        for (int i = 0; i < NL; ++i) {
            if (r + 4 * i < nrows)
                lx4[(r + 4 * i) * LSTR4 + wcol] = pf[i];  // ds_write_b128
        }
    };

    // Prologue: stage group 0 (LDS untouched yet -> no pre-barrier).
    issue(0);
    commit();
    __syncthreads();

#pragma unroll 1
    for (int g = 0; g < G4; ++g) {
        // T14 issue-early: next group's global loads start NOW and have
        // the whole gather below (~2600 cy) to land. The vmcnt(0) inside
        // the next __syncthreads is then free.
        if (g + 1 < G4) issue(g + 1);

        const float* wg = wgt + (size_t)(c0 + 4 * g) * 9;
        float ax = 0.f, ay = 0.f, az = 0.f, aw = 0.f;
#pragma unroll
        for (int kk = 0; kk < 9; ++kk) {
            const int q = lofs[kk];
            const float4 A0 = lx4[q];
            const float4 A1 = lx4[q + 1];
            const float4 B0 = lx4[q + LSTR4];
            const float4 B1 = lx4[q + LSTR4 + 1];
            const float c0w = cw[kk][0], c1w = cw[kk][1];
            const float c2w = cw[kk][2], c3w = cw[kk][3];
            float sx = c0w * A0.x; sx = fmaf(c1w, A1.x, sx);
            sx = fmaf(c2w, B0.x, sx); sx = fmaf(c3w, B1.x, sx);
            float sy = c0w * A0.y; sy = fmaf(c1w, A1.y, sy);
            sy = fmaf(c2w, B0.y, sy); sy = fmaf(c3w, B1.y, sy);
            float sz = c0w * A0.z; sz = fmaf(c1w, A1.z, sz);
            sz = fmaf(c2w, B0.z, sz); sz = fmaf(c3w, B1.z, sz);
            float sw = c0w * A0.w; sw = fmaf(c1w, A1.w, sw);
            sw = fmaf(c2w, B0.w, sw); sw = fmaf(c3w, B1.w, sw);
            ax = fmaf(wg[kk],      sx, ax);
            ay = fmaf(wg[9 + kk],  sy, ay);
            az = fmaf(wg[18 + kk], sz, az);
            aw = fmaf(wg[27 + kk], sw, aw);
        }
        const int cg = c0 + 4 * g;
        outb[(size_t)(4 * g + 0) * HW_] = ax + bias[cg + 0];
        outb[(size_t)(4 * g + 1) * HW_] = ay + bias[cg + 1];
        outb[(size_t)(4 * g + 2) * HW_] = az + bias[cg + 2];
        outb[(size_t)(4 * g + 3) * HW_] = aw + bias[cg + 3];

        if (g + 1 < G4) {
            __syncthreads();           // readers of group g done
            commit();                  // write-late: pf -> LDS (padded)
            __syncthreads();           // staged & visible
        }
    }
}

extern "C" void kernel_launch(void* const* d_in, const int* in_sizes, int n_in,
                              void* d_out, int out_size, void* d_ws, size_t ws_size,
                              hipStream_t stream) {
    const float* x    = (const float*)d_in[0];
    const float* off  = (const float*)d_in[1];
    const float* w    = (const float*)d_in[2];
    const float* bias = (const float*)d_in[3];
    float* out        = (float*)d_out;
    dim3 grid(H_ / TH, B_, CSPLIT);
    deform_dw_conv<<<grid, NT, 0, stream>>>(x, off, w, bias, out);
}

// Round 7
// 254.335 us; speedup vs baseline: 1.0284x; 1.0284x over previous
//
#include <hip/hip_runtime.h>

// Deformable depthwise 3x3 conv, B=8 C=256 H=W=96, fp32.
// Ladder: R5 166 -> R9 152 (channel-interleaved float4 gather, conflicts
//   3.17e7->1.46e7) -> R10 131 (T14 issue-early/write-late, CAP=20).
// R11 REFUTED: stride-97 pad -> conflicts +8%, dur 164us (extra live state
//   broke addressing CSE; stride-96 quads were already balanced). Reverted.
// R6/R8 lessons: min-waves bounds / asm pipelines spill cw[9][4] to HBM
//   scratch -> plain __syncthreads + unbounded allocator ONLY.
// R10 budget (corrected): grid 1536 blocks = 6/CU; VGPR 68->72 alloc ->
//   7 waves/SIMD -> 4 blocks resident -> rounds {4,2}: ~1/3 of kernel at
//   half occupancy (pure tail). LDS pipe ~50% busy. Stall/occupancy-bound.
// R12: (a) revert to R10 layout exactly (stride 96);
//      (b) CSPLIT 8->16: 3072 blocks = 12/CU = 3 EXACT rounds of 4 -> no
//          ragged tail. Cost: offset prologue x2 (~+3us).
//      (c) CAP 20->16 (NL=4): pf 20->16 regs, LDS 24.6KB; if VGPR lands
//          <=64 -> 8 waves/SIMD -> 5 blocks resident. nrows>16 is ~4-sigma
//          block event -> correct fallback path.
// Tripwires: WRITE_SIZE == 73728 KB exactly; conflicts ~1.46e7 (must match
//   R10); VGPR watch for the 64 band.

constexpr int B_ = 8, C_ = 256, H_ = 96, W_ = 96;
constexpr int HW_ = H_ * W_;
constexpr int TH = 4;              // pixel rows per block
constexpr int NT = TH * W_;        // 384 threads = 6 waves
constexpr int CSPLIT = 16;
constexpr int CPB = C_ / CSPLIT;   // 16 channels per block
constexpr int G4 = CPB / 4;        // 4 groups of 4 interleaved channels
constexpr int CAP = 16;            // window rows (typ ~14 used)
constexpr int NPOS = CAP * W_;     // 1536 float4s = 24576 B
constexpr int NL = CAP / TH;       // 4 staging chunks per thread

__global__ __launch_bounds__(NT) void deform_dw_conv(
    const float* __restrict__ x, const float* __restrict__ off,
    const float* __restrict__ wgt, const float* __restrict__ bias,
    float* __restrict__ out)
{
    __shared__ float4 lx4[NPOS];   // [pos] = 4 channels at spatial pos
    __shared__ int s_rmin, s_rmax;

    const int tid  = threadIdx.x;
    const int r    = tid / W_;
    const int wcol = tid - r * W_;
    const int h    = blockIdx.x * TH + r;
    const int b    = blockIdx.y;
    const int c0   = blockIdx.z * CPB;

    if (tid == 0) { s_rmin = H_; s_rmax = -1; }
    __syncthreads();

    const float* offp = off + (size_t)b * 18 * HW_ + (size_t)h * W_ + wcol;

    // Per-(pixel,tap): 4 weights pre-permuted onto loaded positions
    // [0]=(yc,xc) [1]=(yc,xc+1) [2]=(yc+1,xc) [3]=(yc+1,xc+1); validity
    // folded into weights so invalid corners multiply by 0.
    float cw[9][4];
    int lofs[9];
    int myrmin = H_, myrmax = -1;

#pragma unroll
    for (int kk = 0; kk < 9; ++kk) {
        const int i = kk / 3, j = kk % 3;
        const float py = (float)(h - 1 + i) + offp[(2 * kk) * HW_];
        const float px = (float)(wcol - 1 + j) + offp[(2 * kk + 1) * HW_];
        const float fy = floorf(py), fx = floorf(px);
        const float wy = py - fy, wx = px - fx;
        const int y0 = (int)fy, x0 = (int)fx;
        const bool vy0 = (unsigned)y0 < (unsigned)H_;
        const bool vy1 = (unsigned)(y0 + 1) < (unsigned)H_;
        const bool vx0 = (unsigned)x0 < (unsigned)W_;
        const bool vx1 = (unsigned)(x0 + 1) < (unsigned)W_;
        const float w00 = (vy0 && vx0) ? (1.f - wy) * (1.f - wx) : 0.f;
        const float w01 = (vy0 && vx1) ? (1.f - wy) * wx : 0.f;
        const float w10 = (vy1 && vx0) ? wy * (1.f - wx) : 0.f;
        const float w11 = (vy1 && vx1) ? wy * wx : 0.f;
        const int yc = min(max(y0, 0), H_ - 2);
        const int xc = min(max(x0, 0), W_ - 2);
        const bool rs = (y0 == yc);
        const bool cs = (x0 == xc);
        cw[kk][0] = rs ? (cs ? w00 : w01) : (cs ? w10 : w11);
        cw[kk][1] = rs ? (cs ? w01 : w00) : (cs ? w11 : w10);
        cw[kk][2] = rs ? (cs ? w10 : w11) : (cs ? w00 : w01);
        cw[kk][3] = rs ? (cs ? w11 : w10) : (cs ? w01 : w00);
        lofs[kk] = yc * W_ + xc;
        myrmin = min(myrmin, yc);
        myrmax = max(myrmax, yc);
    }
    atomicMin(&s_rmin, myrmin);
    atomicMax(&s_rmax, myrmax);
    __syncthreads();
    const int rmin  = s_rmin;
    const int nrows = s_rmax + 2 - rmin;   // rows [rmin, rmax+1]
    const int pix   = h * W_ + wcol;

    if (nrows > CAP) {
        // Cold correctness path (~4-sigma block event): direct global
        // gather; clamped coords always in-bounds, zero weights neutralize
        // invalid corners. Block-uniform branch; no barriers after this.
        const float* xp = x + (size_t)(b * C_ + c0) * HW_;
        float* op = out + (size_t)(b * C_ + c0) * HW_ + pix;
        for (int cc = 0; cc < CPB; ++cc) {
            float acc = 0.f;
#pragma unroll
            for (int kk = 0; kk < 9; ++kk) {
                const float* q = xp + lofs[kk];
                float s = cw[kk][0] * q[0];
                s = fmaf(cw[kk][1], q[1], s);
                s = fmaf(cw[kk][2], q[W_], s);
                s = fmaf(cw[kk][3], q[W_ + 1], s);
                acc = fmaf(wgt[(c0 + cc) * 9 + kk], s, acc);
            }
            *op = acc + bias[c0 + cc];
            xp += HW_; op += HW_;
        }
        return;
    }

#pragma unroll
    for (int kk = 0; kk < 9; ++kk) lofs[kk] -= rmin * W_;

    const int P = nrows * W_;              // active positions (<= NPOS)
    const float* xbase = x + (size_t)(b * C_ + c0) * HW_ + rmin * W_;
    float* outb = out + (size_t)(b * C_ + c0) * HW_ + pix;

    // Transposed reg-staging for one 4-channel group (R10 form: linear
    // chunks, dense stride-96 LDS rows).
    float4 pf[NL];
    auto issue = [&](int g) {
        const float* p0 = xbase + (size_t)(4 * g) * HW_;
        const float* p1 = p0 + HW_;
        const float* p2 = p1 + HW_;
        const float* p3 = p2 + HW_;
#pragma unroll
        for (int i = 0; i < NL; ++i) {
            const int p = tid + i * NT;
            if (p < P) {
                pf[i].x = p0[p]; pf[i].y = p1[p];
                pf[i].z = p2[p]; pf[i].w = p3[p];
            }
        }
    };
    auto commit = [&]() {
#pragma unroll
        for (int i = 0; i < NL; ++i) {
            const int p = tid + i * NT;
            if (p < P) lx4[p] = pf[i];     // ds_write_b128, quads spread
        }
    };

    // Prologue: stage group 0 (LDS untouched yet -> no pre-barrier).
    issue(0);
    commit();
    __syncthreads();

#pragma unroll 1
    for (int g = 0; g < G4; ++g) {
        // T14 issue-early: next group's global loads start NOW and have
        // the whole gather below (~2600 cy) to land. The vmcnt(0) inside
        // the next __syncthreads is then free.
        if (g + 1 < G4) issue(g + 1);

        const float* wg = wgt + (size_t)(c0 + 4 * g) * 9;
        float ax = 0.f, ay = 0.f, az = 0.f, aw = 0.f;
#pragma unroll
        for (int kk = 0; kk < 9; ++kk) {
            const int q = lofs[kk];
            const float4 A0 = lx4[q];
            const float4 A1 = lx4[q + 1];
            const float4 B0 = lx4[q + W_];
            const float4 B1 = lx4[q + W_ + 1];
            const float c0w = cw[kk][0], c1w = cw[kk][1];
            const float c2w = cw[kk][2], c3w = cw[kk][3];
            float sx = c0w * A0.x; sx = fmaf(c1w, A1.x, sx);
            sx = fmaf(c2w, B0.x, sx); sx = fmaf(c3w, B1.x, sx);
            float sy = c0w * A0.y; sy = fmaf(c1w, A1.y, sy);
            sy = fmaf(c2w, B0.y, sy); sy = fmaf(c3w, B1.y, sy);
            float sz = c0w * A0.z; sz = fmaf(c1w, A1.z, sz);
            sz = fmaf(c2w, B0.z, sz); sz = fmaf(c3w, B1.z, sz);
            float sw = c0w * A0.w; sw = fmaf(c1w, A1.w, sw);
            sw = fmaf(c2w, B0.w, sw); sw = fmaf(c3w, B1.w, sw);
            ax = fmaf(wg[kk],      sx, ax);
            ay = fmaf(wg[9 + kk],  sy, ay);
            az = fmaf(wg[18 + kk], sz, az);
            aw = fmaf(wg[27 + kk], sw, aw);
        }
        const int cg = c0 + 4 * g;
        outb[(size_t)(4 * g + 0) * HW_] = ax + bias[cg + 0];
        outb[(size_t)(4 * g + 1) * HW_] = ay + bias[cg + 1];
        outb[(size_t)(4 * g + 2) * HW_] = az + bias[cg + 2];
        outb[(size_t)(4 * g + 3) * HW_] = aw + bias[cg + 3];

        if (g + 1 < G4) {
            __syncthreads();           // readers of group g done
            commit();                  // write-late: pf -> LDS
            __syncthreads();           // staged & visible
        }
    }
}

extern "C" void kernel_launch(void* const* d_in, const int* in_sizes, int n_in,
                              void* d_out, int out_size, void* d_ws, size_t ws_size,
                              hipStream_t stream) {
    const float* x    = (const float*)d_in[0];
    const float* off  = (const float*)d_in[1];
    const float* w    = (const float*)d_in[2];
    const float* bias = (const float*)d_in[3];
    float* out        = (float*)d_out;
    dim3 grid(H_ / TH, B_, CSPLIT);
    deform_dw_conv<<<grid, NT, 0, stream>>>(x, off, w, bias, out);
}

// Round 8
// 206.783 us; speedup vs baseline: 1.2649x; 1.2300x over previous
//
#include <hip/hip_runtime.h>

// Deformable depthwise 3x3 conv, B=8 C=256 H=W=96, fp32.
// Ladder: R5 166 -> R9 152 (channel-interleaved float4 gather, conflicts
//   3.17e7->1.46e7; 9 b128 reads/px-ch = info-theoretic floor of b128
//   gather) -> R10 131 (T14 issue-early/write-late, CAP=20, CSPLIT=8).
// R11 REFUTED: stride-97 pad -> conflicts +8%, 164us. R12 REFUTED: CSPLIT
//   16 -> 160us, but MEASURED per-block serial overhead = ~12k cy/block
//   => ~30us of R10's wall is prologue serialization (init barrier, 18
//   strided offset loads, atomicMin/Max+barrier for rmin, serial
//   issue(0)->commit->barrier).
// R6/R8 lessons: min-waves bounds / asm pipelines spill cw[9][4] to HBM
//   scratch -> plain __syncthreads + unbounded allocator ONLY.
// R13: STATIC window wlo = clamp(h0-8, 0, 76), always CAP=20 rows:
//   - no rmin atomics/barrier, no init barrier, branch-free staging
//     (NL*NT == window exactly);
//   - issue(0) depends only on blockIdx -> issued FIRST, global latency
//     hides under the whole offset/floorf prologue;
//   - coverage >=6-sigma interior, edge blocks always covered (clamp
//     rescues); exact fallback via __syncthreads_and coverage check.
//   Body (gather/phase/barrier structure) is R10 unchanged.
// Tripwires: WRITE_SIZE == 73728 KB exactly; conflicts ~1.463e7;
//   VGPR <= 84 (4 blocks resident), alarm if >85.

constexpr int B_ = 8, C_ = 256, H_ = 96, W_ = 96;
constexpr int HW_ = H_ * W_;
constexpr int TH = 4;              // pixel rows per block
constexpr int NT = TH * W_;        // 384 threads = 6 waves
constexpr int CSPLIT = 8;
constexpr int CPB = C_ / CSPLIT;   // 32 channels per block
constexpr int G4 = CPB / 4;        // 8 groups of 4 interleaved channels
constexpr int CAP = 20;            // static window rows
constexpr int NPOS = CAP * W_;     // 1920 positions = 30720 B as float4
constexpr int NL = NPOS / NT;      // 5 staging chunks (exact, no remainder)
constexpr int PAD_UP = 8;          // rows staged above block's first row

__global__ __launch_bounds__(NT) void deform_dw_conv(
    const float* __restrict__ x, const float* __restrict__ off,
    const float* __restrict__ wgt, const float* __restrict__ bias,
    float* __restrict__ out)
{
    __shared__ float4 lx4[NPOS];   // [pos] = 4 channels at spatial pos

    const int tid  = threadIdx.x;
    const int r    = tid / W_;
    const int wcol = tid - r * W_;
    const int h0   = blockIdx.x * TH;
    const int h    = h0 + r;
    const int b    = blockIdx.y;
    const int c0   = blockIdx.z * CPB;

    // Static staging window: rows [wlo, wlo+CAP). Interior margin >=6sigma;
    // when wlo==0 the low clamp always covers, when wlo==76 the high side
    // always covers (yc <= 94 == 76+18).
    const int wlo = min(max(h0 - PAD_UP, 0), H_ - CAP);

    const float* xbase = x + (size_t)(b * C_ + c0) * HW_ + wlo * W_;

    // Transposed reg-staging, branch-free: chunk i covers position
    // tid + i*NT of the 1920-position window (dense in global and LDS).
    float4 pf[NL];
    auto issue = [&](int g) {
        const float* p0 = xbase + (size_t)(4 * g) * HW_;
        const float* p1 = p0 + HW_;
        const float* p2 = p1 + HW_;
        const float* p3 = p2 + HW_;
#pragma unroll
        for (int i = 0; i < NL; ++i) {
            const int p = tid + i * NT;
            pf[i].x = p0[p]; pf[i].y = p1[p];
            pf[i].z = p2[p]; pf[i].w = p3[p];
        }
    };
    auto commit = [&]() {
#pragma unroll
        for (int i = 0; i < NL; ++i)
            lx4[tid + i * NT] = pf[i];     // ds_write_b128, quads spread
    };

    // Issue group-0 staging FIRST: depends only on blockIdx, so its global
    // latency hides under the entire offset prologue below.
    issue(0);

    const float* offp = off + (size_t)b * 18 * HW_ + (size_t)h * W_ + wcol;

    // Per-(pixel,tap): 4 weights pre-permuted onto loaded positions
    // [0]=(yc,xc) [1]=(yc,xc+1) [2]=(yc+1,xc) [3]=(yc+1,xc+1); validity
    // folded into weights so invalid corners multiply by 0.
    float cw[9][4];
    int lofs[9];                     // window-relative (yc-wlo)*96+xc
    int ok = 1;

#pragma unroll
    for (int kk = 0; kk < 9; ++kk) {
        const int i = kk / 3, j = kk % 3;
        const float py = (float)(h - 1 + i) + offp[(2 * kk) * HW_];
        const float px = (float)(wcol - 1 + j) + offp[(2 * kk + 1) * HW_];
        const float fy = floorf(py), fx = floorf(px);
        const float wy = py - fy, wx = px - fx;
        const int y0 = (int)fy, x0 = (int)fx;
        const bool vy0 = (unsigned)y0 < (unsigned)H_;
        const bool vy1 = (unsigned)(y0 + 1) < (unsigned)H_;
        const bool vx0 = (unsigned)x0 < (unsigned)W_;
        const bool vx1 = (unsigned)(x0 + 1) < (unsigned)W_;
        const float w00 = (vy0 && vx0) ? (1.f - wy) * (1.f - wx) : 0.f;
        const float w01 = (vy0 && vx1) ? (1.f - wy) * wx : 0.f;
        const float w10 = (vy1 && vx0) ? wy * (1.f - wx) : 0.f;
        const float w11 = (vy1 && vx1) ? wy * wx : 0.f;
        const int yc = min(max(y0, 0), H_ - 2);
        const int xc = min(max(x0, 0), W_ - 2);
        const bool rs = (y0 == yc);
        const bool cs = (x0 == xc);
        cw[kk][0] = rs ? (cs ? w00 : w01) : (cs ? w10 : w11);
        cw[kk][1] = rs ? (cs ? w01 : w00) : (cs ? w11 : w10);
        cw[kk][2] = rs ? (cs ? w10 : w11) : (cs ? w00 : w01);
        cw[kk][3] = rs ? (cs ? w11 : w10) : (cs ? w01 : w00);
        lofs[kk] = (yc - wlo) * W_ + xc;
        ok &= (yc >= wlo) & (yc <= wlo + CAP - 2);
    }

    const int pix = h * W_ + wcol;

    // Block-uniform coverage decision (replaces the atomic rmin round).
    if (!__syncthreads_and(ok)) {
        // Cold correctness path (>=6-sigma block event): direct global
        // gather; lofs+wlo*W_ is the absolute plane offset regardless of
        // sign. Clamped coords always in-bounds; zero weights neutralize
        // invalid corners. Block-uniform branch; no barriers after this.
        const float* xp = x + (size_t)(b * C_ + c0) * HW_ + wlo * W_;
        float* op = out + (size_t)(b * C_ + c0) * HW_ + pix;
        for (int cc = 0; cc < CPB; ++cc) {
            float acc = 0.f;
#pragma unroll
            for (int kk = 0; kk < 9; ++kk) {
                const float* q = xp + lofs[kk];
                float s = cw[kk][0] * q[0];
                s = fmaf(cw[kk][1], q[1], s);
                s = fmaf(cw[kk][2], q[W_], s);
                s = fmaf(cw[kk][3], q[W_ + 1], s);
                acc = fmaf(wgt[(c0 + cc) * 9 + kk], s, acc);
            }
            *op = acc + bias[c0 + cc];
            xp += HW_; op += HW_;
        }
        return;
    }

    // Hot path: group-0 loads have been in flight since the top.
    commit();
    __syncthreads();

    float* outb = out + (size_t)(b * C_ + c0) * HW_ + pix;

#pragma unroll 1
    for (int g = 0; g < G4; ++g) {
        // T14 issue-early: next group's global loads start NOW and have
        // the whole gather below (~2600 cy) to land. The vmcnt(0) inside
        // the next __syncthreads is then free.
        if (g + 1 < G4) issue(g + 1);

        const float* wg = wgt + (size_t)(c0 + 4 * g) * 9;
        float ax = 0.f, ay = 0.f, az = 0.f, aw = 0.f;
#pragma unroll
        for (int kk = 0; kk < 9; ++kk) {
            const int q = lofs[kk];
            const float4 A0 = lx4[q];
            const float4 A1 = lx4[q + 1];
            const float4 B0 = lx4[q + W_];
            const float4 B1 = lx4[q + W_ + 1];
            const float c0w = cw[kk][0], c1w = cw[kk][1];
            const float c2w = cw[kk][2], c3w = cw[kk][3];
            float sx = c0w * A0.x; sx = fmaf(c1w, A1.x, sx);
            sx = fmaf(c2w, B0.x, sx); sx = fmaf(c3w, B1.x, sx);
            float sy = c0w * A0.y; sy = fmaf(c1w, A1.y, sy);
            sy = fmaf(c2w, B0.y, sy); sy = fmaf(c3w, B1.y, sy);
            float sz = c0w * A0.z; sz = fmaf(c1w, A1.z, sz);
            sz = fmaf(c2w, B0.z, sz); sz = fmaf(c3w, B1.z, sz);
            float sw = c0w * A0.w; sw = fmaf(c1w, A1.w, sw);
            sw = fmaf(c2w, B0.w, sw); sw = fmaf(c3w, B1.w, sw);
            ax = fmaf(wg[kk],      sx, ax);
            ay = fmaf(wg[9 + kk],  sy, ay);
            az = fmaf(wg[18 + kk], sz, az);
            aw = fmaf(wg[27 + kk], sw, aw);
        }
        const int cg = c0 + 4 * g;
        outb[(size_t)(4 * g + 0) * HW_] = ax + bias[cg + 0];
        outb[(size_t)(4 * g + 1) * HW_] = ay + bias[cg + 1];
        outb[(size_t)(4 * g + 2) * HW_] = az + bias[cg + 2];
        outb[(size_t)(4 * g + 3) * HW_] = aw + bias[cg + 3];

        if (g + 1 < G4) {
            __syncthreads();           // readers of group g done
            commit();                  // write-late: pf -> LDS
            __syncthreads();           // staged & visible
        }
    }
}

extern "C" void kernel_launch(void* const* d_in, const int* in_sizes, int n_in,
                              void* d_out, int out_size, void* d_ws, size_t ws_size,
                              hipStream_t stream) {
    const float* x    = (const float*)d_in[0];
    const float* off  = (const float*)d_in[1];
    const float* w    = (const float*)d_in[2];
    const float* bias = (const float*)d_in[3];
    float* out        = (float*)d_out;
    dim3 grid(H_ / TH, B_, CSPLIT);
    deform_dw_conv<<<grid, NT, 0, stream>>>(x, off, w, bias, out);
}

// Round 9
// 181.439 us; speedup vs baseline: 1.4415x; 1.1397x over previous
//
#include <hip/hip_runtime.h>

// Deformable depthwise 3x3 conv, B=8 C=256 H=W=96, fp32.
// Ladder: R5 166 -> R9 152 (channel-interleaved float4 gather: conflicts
//   3.17e7->1.46e7; 9 b128/px-ch = info floor) -> R10 131 (T14 issue-early/
//   write-late) -> R13 110.6 (static window, no rmin atomics, issue-first).
// REFUTED: R11 stride-97 pad (conflicts +8%); R12 CSPLIT=16 (per-block
//   overhead ~12k cy dominates); R6/R8 launch-bounds/asm pipelines (spill).
// R13 budget per CU: gather 124k cy + conflicts 57k + writes 17k = 198k cy
//   = 83us LDS-pipe busy vs 110.6us wall (75%). Read count at info floor;
//   conflicts are statistical jitter imbalance (layout-irreducible, R11).
//   Remaining 28us = per-block prologue latency + 16 barrier skews/block.
// R14: TH 4->8 (NT=768, 12 waves, CAP=24, PAD_UP=8):
//   - prologue count halves (1536->768 blocks);
//   - staging amplification 5x->3x: FETCH 200->~150 MB;
//   - pf 5->3 chunks (-8 VGPR); barrier events halve;
//   - residency unchanged: 2 blocks x 12 = 24 waves/CU (== 4x6) for any
//     VGPR <= 84 -> isolates prologue/fetch effect.
//   Gather layout/rhythm byte-identical to R13.
// Tripwires: WRITE_SIZE == 73728 KB exactly; conflicts ~1.463e7.

constexpr int B_ = 8, C_ = 256, H_ = 96, W_ = 96;
constexpr int HW_ = H_ * W_;
constexpr int TH = 8;              // pixel rows per block
constexpr int NT = TH * W_;        // 768 threads = 12 waves
constexpr int CSPLIT = 8;
constexpr int CPB = C_ / CSPLIT;   // 32 channels per block
constexpr int G4 = CPB / 4;        // 8 groups of 4 interleaved channels
constexpr int CAP = 24;            // static window rows
constexpr int NPOS = CAP * W_;     // 2304 positions = 36864 B as float4
constexpr int NL = NPOS / NT;      // 3 staging chunks (exact, no remainder)
constexpr int PAD_UP = 8;          // rows staged above block's first row

__global__ __launch_bounds__(NT) void deform_dw_conv(
    const float* __restrict__ x, const float* __restrict__ off,
    const float* __restrict__ wgt, const float* __restrict__ bias,
    float* __restrict__ out)
{
    __shared__ float4 lx4[NPOS];   // [pos] = 4 channels at spatial pos

    const int tid  = threadIdx.x;
    const int r    = tid / W_;
    const int wcol = tid - r * W_;
    const int h0   = blockIdx.x * TH;
    const int h    = h0 + r;
    const int b    = blockIdx.y;
    const int c0   = blockIdx.z * CPB;

    // Static staging window: rows [wlo, wlo+CAP). Interior lower margin
    // >=6sigma, upper >=7sigma; at the edges the clamps always cover.
    const int wlo = min(max(h0 - PAD_UP, 0), H_ - CAP);

    const float* xbase = x + (size_t)(b * C_ + c0) * HW_ + wlo * W_;

    // Transposed reg-staging, branch-free: chunk i covers position
    // tid + i*NT of the 2304-position window (dense in global and LDS).
    float4 pf[NL];
    auto issue = [&](int g) {
        const float* p0 = xbase + (size_t)(4 * g) * HW_;
        const float* p1 = p0 + HW_;
        const float* p2 = p1 + HW_;
        const float* p3 = p2 + HW_;
#pragma unroll
        for (int i = 0; i < NL; ++i) {
            const int p = tid + i * NT;
            pf[i].x = p0[p]; pf[i].y = p1[p];
            pf[i].z = p2[p]; pf[i].w = p3[p];
        }
    };
    auto commit = [&]() {
#pragma unroll
        for (int i = 0; i < NL; ++i)
            lx4[tid + i * NT] = pf[i];     // ds_write_b128, quads spread
    };

    // Issue group-0 staging FIRST: depends only on blockIdx, so its global
    // latency hides under the entire offset prologue below.
    issue(0);

    const float* offp = off + (size_t)b * 18 * HW_ + (size_t)h * W_ + wcol;

    // Per-(pixel,tap): 4 weights pre-permuted onto loaded positions
    // [0]=(yc,xc) [1]=(yc,xc+1) [2]=(yc+1,xc) [3]=(yc+1,xc+1); validity
    // folded into weights so invalid corners multiply by 0.
    float cw[9][4];
    int lofs[9];                     // window-relative (yc-wlo)*96+xc
    int ok = 1;

#pragma unroll
    for (int kk = 0; kk < 9; ++kk) {
        const int i = kk / 3, j = kk % 3;
        const float py = (float)(h - 1 + i) + offp[(2 * kk) * HW_];
        const float px = (float)(wcol - 1 + j) + offp[(2 * kk + 1) * HW_];
        const float fy = floorf(py), fx = floorf(px);
        const float wy = py - fy, wx = px - fx;
        const int y0 = (int)fy, x0 = (int)fx;
        const bool vy0 = (unsigned)y0 < (unsigned)H_;
        const bool vy1 = (unsigned)(y0 + 1) < (unsigned)H_;
        const bool vx0 = (unsigned)x0 < (unsigned)W_;
        const bool vx1 = (unsigned)(x0 + 1) < (unsigned)W_;
        const float w00 = (vy0 && vx0) ? (1.f - wy) * (1.f - wx) : 0.f;
        const float w01 = (vy0 && vx1) ? (1.f - wy) * wx : 0.f;
        const float w10 = (vy1 && vx0) ? wy * (1.f - wx) : 0.f;
        const float w11 = (vy1 && vx1) ? wy * wx : 0.f;
        const int yc = min(max(y0, 0), H_ - 2);
        const int xc = min(max(x0, 0), W_ - 2);
        const bool rs = (y0 == yc);
        const bool cs = (x0 == xc);
        cw[kk][0] = rs ? (cs ? w00 : w01) : (cs ? w10 : w11);
        cw[kk][1] = rs ? (cs ? w01 : w00) : (cs ? w11 : w10);
        cw[kk][2] = rs ? (cs ? w10 : w11) : (cs ? w00 : w01);
        cw[kk][3] = rs ? (cs ? w11 : w10) : (cs ? w01 : w00);
        lofs[kk] = (yc - wlo) * W_ + xc;
        ok &= (yc >= wlo) & (yc <= wlo + CAP - 2);
    }

    const int pix = h * W_ + wcol;

    // Block-uniform coverage decision.
    if (!__syncthreads_and(ok)) {
        // Cold correctness path (rare sigma event): direct global gather;
        // lofs+wlo*W_ is the absolute plane offset. Clamped coords always
        // in-bounds; zero weights neutralize invalid corners.
        const float* xp = x + (size_t)(b * C_ + c0) * HW_ + wlo * W_;
        float* op = out + (size_t)(b * C_ + c0) * HW_ + pix;
        for (int cc = 0; cc < CPB; ++cc) {
            float acc = 0.f;
#pragma unroll
            for (int kk = 0; kk < 9; ++kk) {
                const float* q = xp + lofs[kk];
                float s = cw[kk][0] * q[0];
                s = fmaf(cw[kk][1], q[1], s);
                s = fmaf(cw[kk][2], q[W_], s);
                s = fmaf(cw[kk][3], q[W_ + 1], s);
                acc = fmaf(wgt[(c0 + cc) * 9 + kk], s, acc);
            }
            *op = acc + bias[c0 + cc];
            xp += HW_; op += HW_;
        }
        return;
    }

    // Hot path: group-0 loads have been in flight since the top.
    commit();
    __syncthreads();

    float* outb = out + (size_t)(b * C_ + c0) * HW_ + pix;

#pragma unroll 1
    for (int g = 0; g < G4; ++g) {
        // T14 issue-early: next group's global loads start NOW and have
        // the whole gather below to land. The vmcnt(0) inside the next
        // __syncthreads is then free.
        if (g + 1 < G4) issue(g + 1);

        const float* wg = wgt + (size_t)(c0 + 4 * g) * 9;
        float ax = 0.f, ay = 0.f, az = 0.f, aw = 0.f;
#pragma unroll
        for (int kk = 0; kk < 9; ++kk) {
            const int q = lofs[kk];
            const float4 A0 = lx4[q];
            const float4 A1 = lx4[q + 1];
            const float4 B0 = lx4[q + W_];
            const float4 B1 = lx4[q + W_ + 1];
            const float c0w = cw[kk][0], c1w = cw[kk][1];
            const float c2w = cw[kk][2], c3w = cw[kk][3];
            float sx = c0w * A0.x; sx = fmaf(c1w, A1.x, sx);
            sx = fmaf(c2w, B0.x, sx); sx = fmaf(c3w, B1.x, sx);
            float sy = c0w * A0.y; sy = fmaf(c1w, A1.y, sy);
            sy = fmaf(c2w, B0.y, sy); sy = fmaf(c3w, B1.y, sy);
            float sz = c0w * A0.z; sz = fmaf(c1w, A1.z, sz);
            sz = fmaf(c2w, B0.z, sz); sz = fmaf(c3w, B1.z, sz);
            float sw = c0w * A0.w; sw = fmaf(c1w, A1.w, sw);
            sw = fmaf(c2w, B0.w, sw); sw = fmaf(c3w, B1.w, sw);
            ax = fmaf(wg[kk],      sx, ax);
            ay = fmaf(wg[9 + kk],  sy, ay);
            az = fmaf(wg[18 + kk], sz, az);
            aw = fmaf(wg[27 + kk], sw, aw);
        }
        const int cg = c0 + 4 * g;
        outb[(size_t)(4 * g + 0) * HW_] = ax + bias[cg + 0];
        outb[(size_t)(4 * g + 1) * HW_] = ay + bias[cg + 1];
        outb[(size_t)(4 * g + 2) * HW_] = az + bias[cg + 2];
        outb[(size_t)(4 * g + 3) * HW_] = aw + bias[cg + 3];

        if (g + 1 < G4) {
            __syncthreads();           // readers of group g done
            commit();                  // write-late: pf -> LDS
            __syncthreads();           // staged & visible
        }
    }
}

extern "C" void kernel_launch(void* const* d_in, const int* in_sizes, int n_in,
                              void* d_out, int out_size, void* d_ws, size_t ws_size,
                              hipStream_t stream) {
    const float* x    = (const float*)d_in[0];
    const float* off  = (const float*)d_in[1];
    const float* w    = (const float*)d_in[2];
    const float* bias = (const float*)d_in[3];
    float* out        = (float*)d_out;
    dim3 grid(H_ / TH, B_, CSPLIT);
    deform_dw_conv<<<grid, NT, 0, stream>>>(x, off, w, bias, out);
}